// Round 1
// baseline (178.958 us; speedup 1.0000x reference)
//
#include <hip/hip_runtime.h>
#include <hip/hip_bf16.h>
#include <cstdint>

#define BATCH 8192
#define IN_F  4096
#define OUT_F 128
// float32-rounded decay constants (tau_fac=100, tau_dep=200)
#define FD 0.99004983374916811f
#define DD 0.99501247919268232f

typedef __attribute__((ext_vector_type(4))) float f32x4;
typedef __attribute__((ext_vector_type(8))) short bf16x8;

__device__ __forceinline__ unsigned short f2bf(float f){
  union { float f; unsigned u; } v; v.f = f;
  unsigned u = v.u;
  return (unsigned short)((u + 0x7FFFu + ((u >> 16) & 1u)) >> 16);  // RNE
}

// Pre-shuffle weight[128][4096] f32 -> fragment-major bf16 in ws.
// Frag id f = (ks*8 + ct)*64 + l ; lane l holds weight[ct*16+(l&15)][ks*32+(l>>4)*8 + j], j=0..7
__global__ __launch_bounds__(256) void prep_weight_kernel(const float* __restrict__ w,
                                                          unsigned short* __restrict__ wf){
  const int f  = blockIdx.x * 256 + threadIdx.x;   // 0..65535
  const int l  = f & 63;
  const int ct = (f >> 6) & 7;
  const int ks = f >> 9;                           // 0..127
  const int row = ct * 16 + (l & 15);
  const int k   = ks * 32 + ((l >> 4) << 3);
  const f32x4* src = reinterpret_cast<const f32x4*>(w + (size_t)row * IN_F + k);
  f32x4 a = src[0], b = src[1];
  union { bf16x8 v; unsigned short s[8]; } o;
  o.s[0]=f2bf(a[0]); o.s[1]=f2bf(a[1]); o.s[2]=f2bf(a[2]); o.s[3]=f2bf(a[3]);
  o.s[4]=f2bf(b[0]); o.s[5]=f2bf(b[1]); o.s[6]=f2bf(b[2]); o.s[7]=f2bf(b[3]);
  *reinterpret_cast<bf16x8*>(wf + (size_t)f * 8) = o.v;
}

// Fused: streaming STP state update + bf16 MFMA GEMM (out = (s*u*x) @ W^T).
// Block: 256 thr = 4 waves; 16 rows per block; K tiled by 64 (2 MFMA k-steps).
// Wave w owns output col-tiles 2w and 2w+1 (16 cols each) for the 16 rows.
template<bool WS>
__global__ __launch_bounds__(256) void stp_fused_kernel(
    const float* __restrict__ pre, const float* __restrict__ uin,
    const float* __restrict__ xin, const float* __restrict__ w,
    const unsigned short* __restrict__ wf,
    float* __restrict__ out, float* __restrict__ un_out, float* __restrict__ xn_out)
{
  __shared__ unsigned char lds[2][16 * 128];  // 16 rows x 64 k bf16, double-buffered

  const int tid = threadIdx.x;
  const int rl  = tid >> 4;        // local row 0..15
  const int c4  = tid & 15;        // float4 column 0..15
  const int rowBase = blockIdx.x * 16;
  const size_t base = (size_t)(rowBase + rl) * IN_F + (c4 << 2);

  const int l  = tid & 63;
  const int wv = tid >> 6;

  // LDS write addr (8B of 4 bf16), XOR-swizzled by row to kill bank conflicts
  const int wbyte = ((rl * 128) + (c4 << 3)) ^ ((rl & 7) << 4);
  // A-fragment read geometry: lane l -> row l&15, k-chunk (l>>4)*8
  const int arow  = l & 15;
  const int asw   = (arow & 7) << 4;
  const int abase = arow * 128 + ((l >> 4) << 4);

  f32x4 s4 = *reinterpret_cast<const f32x4*>(pre + base);
  f32x4 u4 = *reinterpret_cast<const f32x4*>(uin + base);
  f32x4 x4 = *reinterpret_cast<const f32x4*>(xin + base);

  f32x4 acc0 = {0.f,0.f,0.f,0.f}, acc1 = {0.f,0.f,0.f,0.f};

  for (int ki = 0; ki < 64; ++ki){
    const size_t g = base + (size_t)(ki << 6);

    // ---- elementwise phase: STP update + r = u*x*s in bf16 ----
    f32x4 un, xn;
    uint2 pk;
    {
      unsigned short rb[4];
      #pragma unroll
      for (int j = 0; j < 4; ++j){
        const float s = s4[j], u = u4[j], x = x4[j];
        rb[j] = f2bf(u * x * s);
        const float ufd = u * FD;
        const float unj = ufd + 0.5f * (1.0f - ufd) * s;
        un[j] = unj;
        xn[j] = x * DD + (1.0f - x) * DD * (1.0f - s * unj);
      }
      pk.x = (unsigned)rb[0] | ((unsigned)rb[1] << 16);
      pk.y = (unsigned)rb[2] | ((unsigned)rb[3] << 16);
    }
    *reinterpret_cast<f32x4*>(un_out + g) = un;
    *reinterpret_cast<f32x4*>(xn_out + g) = xn;
    *reinterpret_cast<uint2*>(&lds[ki & 1][wbyte]) = pk;

    __syncthreads();

    // prefetch next tile's inputs; latency hides under MFMA phase + stores
    if (ki < 63){
      const size_t gn = base + (size_t)((ki + 1) << 6);
      s4 = *reinterpret_cast<const f32x4*>(pre + gn);
      u4 = *reinterpret_cast<const f32x4*>(uin + gn);
      x4 = *reinterpret_cast<const f32x4*>(xin + gn);
    }

    // ---- MFMA phase ----
    const unsigned char* buf = lds[ki & 1];
    #pragma unroll
    for (int t2 = 0; t2 < 2; ++t2){
      const int ab = (abase + (t2 << 6)) ^ asw;   // full logical offset, then swizzle
      bf16x8 af = *reinterpret_cast<const bf16x8*>(buf + ab);
      bf16x8 b0f, b1f;
      const int ks = (ki << 1) + t2;
      if (WS){
        const bf16x8* wfp = reinterpret_cast<const bf16x8*>(wf);
        b0f = wfp[(size_t)((ks * 8 + 2 * wv)     * 64 + l)];
        b1f = wfp[(size_t)((ks * 8 + 2 * wv + 1) * 64 + l)];
      } else {
        const int kg = ks * 32 + ((l >> 4) << 3);
        const int r0 = (2 * wv) * 16 + (l & 15);
        const f32x4* p0 = reinterpret_cast<const f32x4*>(w + (size_t)r0 * IN_F + kg);
        const f32x4* p1 = reinterpret_cast<const f32x4*>(w + (size_t)(r0 + 16) * IN_F + kg);
        f32x4 a0 = p0[0], a1 = p0[1], c0 = p1[0], c1 = p1[1];
        union { bf16x8 v; unsigned short s[8]; } t;
        t.s[0]=f2bf(a0[0]); t.s[1]=f2bf(a0[1]); t.s[2]=f2bf(a0[2]); t.s[3]=f2bf(a0[3]);
        t.s[4]=f2bf(a1[0]); t.s[5]=f2bf(a1[1]); t.s[6]=f2bf(a1[2]); t.s[7]=f2bf(a1[3]);
        b0f = t.v;
        t.s[0]=f2bf(c0[0]); t.s[1]=f2bf(c0[1]); t.s[2]=f2bf(c0[2]); t.s[3]=f2bf(c0[3]);
        t.s[4]=f2bf(c1[0]); t.s[5]=f2bf(c1[1]); t.s[6]=f2bf(c1[2]); t.s[7]=f2bf(c1[3]);
        b1f = t.v;
      }
      acc0 = __builtin_amdgcn_mfma_f32_16x16x32_bf16(af, b0f, acc0, 0, 0, 0);
      acc1 = __builtin_amdgcn_mfma_f32_16x16x32_bf16(af, b1f, acc1, 0, 0, 0);
    }
  }

  // ---- epilogue: C/D layout col=lane&15, row=(lane>>4)*4+reg ----
  const int colBase = wv * 32 + (l & 15);
  const int rbase   = rowBase + ((l >> 4) << 2);
  #pragma unroll
  for (int rg = 0; rg < 4; ++rg){
    out[(size_t)(rbase + rg) * OUT_F + colBase]      = acc0[rg];
    out[(size_t)(rbase + rg) * OUT_F + colBase + 16] = acc1[rg];
  }
}

extern "C" void kernel_launch(void* const* d_in, const int* in_sizes, int n_in,
                              void* d_out, int out_size, void* d_ws, size_t ws_size,
                              hipStream_t stream){
  const float* pre = (const float*)d_in[0];
  const float* w   = (const float*)d_in[1];
  const float* u   = (const float*)d_in[2];
  const float* x   = (const float*)d_in[3];
  float* out    = (float*)d_out;
  float* un_out = out + (size_t)BATCH * OUT_F;
  float* xn_out = un_out + (size_t)BATCH * IN_F;
  unsigned short* wf = (unsigned short*)d_ws;

  const bool use_ws = (ws_size >= (size_t)(1 << 20));
  if (use_ws){
    prep_weight_kernel<<<256, 256, 0, stream>>>(w, wf);
    stp_fused_kernel<true><<<512, 256, 0, stream>>>(pre, u, x, w, wf, out, un_out, xn_out);
  } else {
    stp_fused_kernel<false><<<512, 256, 0, stream>>>(pre, u, x, w, nullptr, out, un_out, xn_out);
  }
}

// Round 2
// 174.409 us; speedup vs baseline: 1.0261x; 1.0261x over previous
//
#include <hip/hip_runtime.h>
#include <hip/hip_bf16.h>
#include <cstdint>

#define BATCH 8192
#define IN_F  4096
#define OUT_F 128
#define KSPLIT 4
#define KSLICE (IN_F / KSPLIT)   // 1024
// float32-rounded decay constants (tau_fac=100, tau_dep=200)
#define FD 0.99004983374916811f
#define DD 0.99501247919268232f

typedef __attribute__((ext_vector_type(4))) float f32x4;
typedef __attribute__((ext_vector_type(8))) short bf16x8;

__device__ __forceinline__ unsigned short f2bf(float f){
  union { float f; unsigned u; } v; v.f = f;
  unsigned u = v.u;
  return (unsigned short)((u + 0x7FFFu + ((u >> 16) & 1u)) >> 16);  // RNE
}

// Pre-shuffle weight[128][4096] f32 -> fragment-major bf16 in ws.
// Frag id f = (ks*8 + ct)*64 + l ; lane l holds weight[ct*16+(l&15)][ks*32+(l>>4)*8 + j], j=0..7
__global__ __launch_bounds__(256) void prep_weight_kernel(const float* __restrict__ w,
                                                          unsigned short* __restrict__ wf){
  const int f  = blockIdx.x * 256 + threadIdx.x;   // 0..65535
  const int l  = f & 63;
  const int ct = (f >> 6) & 7;
  const int ks = f >> 9;                           // 0..127
  const int row = ct * 16 + (l & 15);
  const int k   = ks * 32 + ((l >> 4) << 3);
  const f32x4* src = reinterpret_cast<const f32x4*>(w + (size_t)row * IN_F + k);
  f32x4 a = src[0], b = src[1];
  union { bf16x8 v; unsigned short s[8]; } o;
  o.s[0]=f2bf(a[0]); o.s[1]=f2bf(a[1]); o.s[2]=f2bf(a[2]); o.s[3]=f2bf(a[3]);
  o.s[4]=f2bf(b[0]); o.s[5]=f2bf(b[1]); o.s[6]=f2bf(b[2]); o.s[7]=f2bf(b[3]);
  *reinterpret_cast<bf16x8*>(wf + (size_t)f * 8) = o.v;
}

// Fused: streaming STP state update + bf16 MFMA GEMM (out = (s*u*x) @ W^T).
// Block: 256 thr = 4 waves; 16 rows x 1024-K slice per block (4-way K-split).
// Wave w owns output col-tiles 2w and 2w+1 (16 cols each); partials combined
// with f32 HW atomics (out pre-zeroed by hipMemsetAsync).
template<bool WS>
__global__ __launch_bounds__(256) void stp_fused_kernel(
    const float* __restrict__ pre, const float* __restrict__ uin,
    const float* __restrict__ xin, const float* __restrict__ w,
    const unsigned short* __restrict__ wf,
    float* __restrict__ out, float* __restrict__ un_out, float* __restrict__ xn_out)
{
  __shared__ unsigned char lds[2][16 * 128];  // 16 rows x 64 k bf16, double-buffered

  const int tid = threadIdx.x;
  const int rl  = tid >> 4;        // local row 0..15
  const int c4  = tid & 15;        // float4 column 0..15
  const int rowBase = (blockIdx.x >> 2) * 16;
  const int kslice  = blockIdx.x & 3;
  const int kbase   = kslice * KSLICE;
  const size_t base = (size_t)(rowBase + rl) * IN_F + kbase + (c4 << 2);

  const int l  = tid & 63;
  const int wv = tid >> 6;

  // LDS write addr (8B of 4 bf16), XOR-swizzled by row to kill bank conflicts
  const int wbyte = ((rl * 128) + (c4 << 3)) ^ ((rl & 7) << 4);
  // A-fragment read geometry: lane l -> row l&15, k-chunk (l>>4)*8
  const int arow  = l & 15;
  const int asw   = (arow & 7) << 4;
  const int abase = arow * 128 + ((l >> 4) << 4);

  f32x4 s4 = *reinterpret_cast<const f32x4*>(pre + base);
  f32x4 u4 = *reinterpret_cast<const f32x4*>(uin + base);
  f32x4 x4 = *reinterpret_cast<const f32x4*>(xin + base);

  f32x4 acc0 = {0.f,0.f,0.f,0.f}, acc1 = {0.f,0.f,0.f,0.f};

  for (int ki = 0; ki < KSLICE / 64; ++ki){
    const size_t g = base + (size_t)(ki << 6);

    // ---- elementwise phase: STP update + r = u*x*s in bf16 ----
    f32x4 un, xn;
    uint2 pk;
    {
      unsigned short rb[4];
      #pragma unroll
      for (int j = 0; j < 4; ++j){
        const float s = s4[j], u = u4[j], x = x4[j];
        rb[j] = f2bf(u * x * s);
        const float ufd = u * FD;
        const float unj = ufd + 0.5f * (1.0f - ufd) * s;
        un[j] = unj;
        xn[j] = x * DD + (1.0f - x) * DD * (1.0f - s * unj);
      }
      pk.x = (unsigned)rb[0] | ((unsigned)rb[1] << 16);
      pk.y = (unsigned)rb[2] | ((unsigned)rb[3] << 16);
    }
    *reinterpret_cast<f32x4*>(un_out + g) = un;
    *reinterpret_cast<f32x4*>(xn_out + g) = xn;
    *reinterpret_cast<uint2*>(&lds[ki & 1][wbyte]) = pk;

    __syncthreads();

    // prefetch next tile's inputs; latency hides under MFMA phase + stores
    if (ki < KSLICE / 64 - 1){
      const size_t gn = base + (size_t)((ki + 1) << 6);
      s4 = *reinterpret_cast<const f32x4*>(pre + gn);
      u4 = *reinterpret_cast<const f32x4*>(uin + gn);
      x4 = *reinterpret_cast<const f32x4*>(xin + gn);
    }

    // ---- MFMA phase ----
    const unsigned char* buf = lds[ki & 1];
    #pragma unroll
    for (int t2 = 0; t2 < 2; ++t2){
      const int ab = (abase + (t2 << 6)) ^ asw;   // full logical offset, then swizzle
      bf16x8 af = *reinterpret_cast<const bf16x8*>(buf + ab);
      bf16x8 b0f, b1f;
      const int ks = (kbase >> 5) + (ki << 1) + t2;   // global k-step index
      if (WS){
        const bf16x8* wfp = reinterpret_cast<const bf16x8*>(wf);
        b0f = wfp[(size_t)((ks * 8 + 2 * wv)     * 64 + l)];
        b1f = wfp[(size_t)((ks * 8 + 2 * wv + 1) * 64 + l)];
      } else {
        const int kg = ks * 32 + ((l >> 4) << 3);
        const int r0 = (2 * wv) * 16 + (l & 15);
        const f32x4* p0 = reinterpret_cast<const f32x4*>(w + (size_t)r0 * IN_F + kg);
        const f32x4* p1 = reinterpret_cast<const f32x4*>(w + (size_t)(r0 + 16) * IN_F + kg);
        f32x4 a0 = p0[0], a1 = p0[1], c0 = p1[0], c1 = p1[1];
        union { bf16x8 v; unsigned short s[8]; } t;
        t.s[0]=f2bf(a0[0]); t.s[1]=f2bf(a0[1]); t.s[2]=f2bf(a0[2]); t.s[3]=f2bf(a0[3]);
        t.s[4]=f2bf(a1[0]); t.s[5]=f2bf(a1[1]); t.s[6]=f2bf(a1[2]); t.s[7]=f2bf(a1[3]);
        b0f = t.v;
        t.s[0]=f2bf(c0[0]); t.s[1]=f2bf(c0[1]); t.s[2]=f2bf(c0[2]); t.s[3]=f2bf(c0[3]);
        t.s[4]=f2bf(c1[0]); t.s[5]=f2bf(c1[1]); t.s[6]=f2bf(c1[2]); t.s[7]=f2bf(c1[3]);
        b1f = t.v;
      }
      acc0 = __builtin_amdgcn_mfma_f32_16x16x32_bf16(af, b0f, acc0, 0, 0, 0);
      acc1 = __builtin_amdgcn_mfma_f32_16x16x32_bf16(af, b1f, acc1, 0, 0, 0);
    }
  }

  // ---- epilogue: C/D layout col=lane&15, row=(lane>>4)*4+reg; K-split partials
  // combined with device-scope f32 HW atomics (out pre-zeroed) ----
  const int colBase = wv * 32 + (l & 15);
  const int rbase   = rowBase + ((l >> 4) << 2);
  #pragma unroll
  for (int rg = 0; rg < 4; ++rg){
    unsafeAtomicAdd(&out[(size_t)(rbase + rg) * OUT_F + colBase],      acc0[rg]);
    unsafeAtomicAdd(&out[(size_t)(rbase + rg) * OUT_F + colBase + 16], acc1[rg]);
  }
}

extern "C" void kernel_launch(void* const* d_in, const int* in_sizes, int n_in,
                              void* d_out, int out_size, void* d_ws, size_t ws_size,
                              hipStream_t stream){
  const float* pre = (const float*)d_in[0];
  const float* w   = (const float*)d_in[1];
  const float* u   = (const float*)d_in[2];
  const float* x   = (const float*)d_in[3];
  float* out    = (float*)d_out;
  float* un_out = out + (size_t)BATCH * OUT_F;
  float* xn_out = un_out + (size_t)BATCH * IN_F;
  unsigned short* wf = (unsigned short*)d_ws;

  // zero the GEMM output region (atomic accumulation target); un/xn are
  // fully overwritten so no init needed there
  hipMemsetAsync(out, 0, (size_t)BATCH * OUT_F * sizeof(float), stream);

  const bool use_ws = (ws_size >= (size_t)(1 << 20));
  const int grid = (BATCH / 16) * KSPLIT;   // 2048 blocks
  if (use_ws){
    prep_weight_kernel<<<256, 256, 0, stream>>>(w, wf);
    stp_fused_kernel<true><<<grid, 256, 0, stream>>>(pre, u, x, w, wf, out, un_out, xn_out);
  } else {
    stp_fused_kernel<false><<<grid, 256, 0, stream>>>(pre, u, x, w, nullptr, out, un_out, xn_out);
  }
}